// Round 18
// baseline (185.616 us; speedup 1.0000x reference)
//
#include <hip/hip_runtime.h>

// ---------------------------------------------------------------------------
// Self-attention (B=4, N=2048, D=1024) on MI355X — fp16, round 18:
// R17 + gemmMS: the proven gemmQKV geometry (1 shared A-tile + 3 B-sets at
// BK=32 -> 192 block-MFMA per barrier pair, 64 KB LDS, 2 blocks/CU) applied
// to scores and PV. Ragged last block via block-uniform runtime set count
// with clamped stage addresses (sync structure byte-identical to gemmQKV).
// conv / gemmQKV / softmax unchanged from R15/R17 (156.7 us best).
// ---------------------------------------------------------------------------

typedef _Float16 hfx8 __attribute__((ext_vector_type(8)));
typedef _Float16 hfx4 __attribute__((ext_vector_type(4)));
typedef float fx4 __attribute__((ext_vector_type(4)));

__device__ __forceinline__ void load_lds16(const void* g, void* l) {
    __builtin_amdgcn_global_load_lds(
        (const __attribute__((address_space(1))) void*)g,
        (__attribute__((address_space(3))) void*)l, 16, 0, 0);
}

template <int N> __device__ __forceinline__ void vmwait() {
    if constexpr (N == 8) asm volatile("s_waitcnt vmcnt(8)" ::: "memory");
    else asm volatile("s_waitcnt vmcnt(0)" ::: "memory");
}

// bijective XCD-chunked grid remap (T1, m204). Requires nwg % 8 == 0.
__device__ __forceinline__ void xcd_remap(int& x, int& y, int& z) {
    const int gx = gridDim.x, gy = gridDim.y;
    const int lin = blockIdx.x + gx * (blockIdx.y + gy * blockIdx.z);
    const int cpx = (gx * gy * gridDim.z) >> 3;
    const int w = (lin & 7) * cpx + (lin >> 3);
    x = w % gx;
    y = (w / gx) % gy;
    z = w / (gx * gy);
}

// ---------------------------------------------------------------------------
// merged converts: blocks [0,8192) -> x (8M floats), [8192,11264) -> Wq/Wk/Wv
// ---------------------------------------------------------------------------
__global__ __launch_bounds__(256) void conv_all_kernel(
    const float4* __restrict__ x, _Float16* __restrict__ xs,
    const float4* __restrict__ w0, const float4* __restrict__ w1, const float4* __restrict__ w2,
    _Float16* __restrict__ o0, _Float16* __restrict__ o1, _Float16* __restrict__ o2)
{
    const int b = blockIdx.x;
    const float4* in;
    _Float16* out;
    long i;
    if (b < 8192) {
        in = x; out = xs;
        i = (long)b * 256 + threadIdx.x;
    } else {
        const int wi = b - 8192;
        const int wsel = wi >> 10;
        in = wsel == 0 ? w0 : (wsel == 1 ? w1 : w2);
        out = wsel == 0 ? o0 : (wsel == 1 ? o1 : o2);
        i = (long)(wi & 1023) * 256 + threadIdx.x;
    }
    float4 v = in[i];
    hfx4 h;
    h[0] = (_Float16)v.x; h[1] = (_Float16)v.y;
    h[2] = (_Float16)v.z; h[3] = (_Float16)v.w;
    *(hfx4*)&out[i * 4] = h;
}

// ---------------------------------------------------------------------------
// gemmQKV (R15, proven 34.7% MfmaUtil): fused Q/K/V projection.
// BM=BN=128, BK=32, 256 thr = 4 waves (2x2). LDS [A|Bq|Bk|Bv] x2 = 64 KB
// -> 2 blocks/CU. 192 block-MFMA per barrier pair. Counted vmcnt(8),
// both-sides swizzle slot^=(row>>1)&3, T5 setprio, T1 XCD remap.
// ---------------------------------------------------------------------------
__global__ __launch_bounds__(256, 2) void gemmQKV(
    const _Float16* __restrict__ A,
    const _Float16* __restrict__ Bq, const _Float16* __restrict__ Bk, const _Float16* __restrict__ Bv,
    const float* __restrict__ bq, const float* __restrict__ bk, const float* __restrict__ bv,
    _Float16* __restrict__ oQ, _Float16* __restrict__ oK, _Float16* __restrict__ oV)
{
    constexpr int BK = 32;
    __shared__ __attribute__((aligned(16))) _Float16 lds[2][4 * 128 * BK]; // 64 KB

    int bx, by, zz;
    xcd_remap(bx, by, zz);

    const int tid = threadIdx.x;
    const int lane = tid & 63;
    const int wv = tid >> 6;
    const int wr = wv >> 1, wc = wv & 1;
    const int lr = lane & 15, lk = lane >> 4;

    const long m0 = (long)by * 128;
    const long n0 = (long)bx * 128;

    fx4 acc[3][4][4] = {};

    auto STAGE = [&](int kt, int b) {
#pragma unroll
        for (int i = 0; i < 8; ++i) {
            const int slot = tid & 3;
            if (i < 2) {
                const int row = i * 64 + (tid >> 2);
                load_lds16(A + (m0 + row) * 1024L + kt + ((slot ^ ((row >> 1) & 3)) << 3),
                           &lds[b][row * BK + slot * 8]);
            } else {
                const int which = (i - 2) >> 1;
                const int row = ((i - 2) & 1) * 64 + (tid >> 2);
                const _Float16* Bsel = which == 0 ? Bq : (which == 1 ? Bk : Bv);
                load_lds16(Bsel + (n0 + row) * 1024L + kt + ((slot ^ ((row >> 1) & 3)) << 3),
                           &lds[b][(1 + which) * 4096 + row * BK + slot * 8]);
            }
        }
    };

    const int NT = 32;
    STAGE(0, 0);
    STAGE(BK, 1);
    vmwait<8>();
    __builtin_amdgcn_s_barrier();
    __builtin_amdgcn_sched_barrier(0);

    const int rA0 = wr * 64 + lr;
    const int rB0 = wc * 64 + lr;
    const int eA = (((rA0 >> 1) & 3) << 3);
    const int eB = (((rB0 >> 1) & 3) << 3);

    for (int t = 0; t < NT; ++t) {
        const _Float16* L = &lds[t & 1][0];

        hfx8 afr[4];
#pragma unroll
        for (int q = 0; q < 4; ++q)
            afr[q] = *(const hfx8*)&L[(rA0 + q * 16) * BK + ((lk * 8) ^ eA)];

#pragma unroll
        for (int w3 = 0; w3 < 3; ++w3) {
            hfx8 bfr[4];
#pragma unroll
            for (int nf = 0; nf < 4; ++nf)
                bfr[nf] = *(const hfx8*)&L[(1 + w3) * 4096 + (rB0 + nf * 16) * BK + ((lk * 8) ^ eB)];
            __builtin_amdgcn_s_setprio(1);
#pragma unroll
            for (int q = 0; q < 4; ++q)
#pragma unroll
                for (int nf = 0; nf < 4; ++nf)
                    acc[w3][q][nf] = __builtin_amdgcn_mfma_f32_16x16x32_f16(
                        afr[q], bfr[nf], acc[w3][q][nf], 0, 0, 0);
            __builtin_amdgcn_s_setprio(0);
        }

        __builtin_amdgcn_s_barrier();
        if (t + 2 < NT) {
            STAGE((t + 2) * BK, t & 1);
            vmwait<8>();
        } else {
            vmwait<0>();
        }
        __builtin_amdgcn_s_barrier();
        __builtin_amdgcn_sched_barrier(0);
    }

#pragma unroll
    for (int w3 = 0; w3 < 3; ++w3) {
#pragma unroll
        for (int mf = 0; mf < 4; ++mf) {
#pragma unroll
            for (int nf = 0; nf < 4; ++nf) {
                const long row0 = m0 + wr * 64 + mf * 16 + lk * 4;
                const long col = n0 + wc * 64 + nf * 16 + lr;
                if (w3 == 0) {
                    const float bb = bq[col];
#pragma unroll
                    for (int j = 0; j < 4; ++j)
                        oQ[(row0 + j) * 1024 + col] = (_Float16)(acc[0][mf][nf][j] + bb);
                } else if (w3 == 1) {
                    const float bb = bk[col];
#pragma unroll
                    for (int j = 0; j < 4; ++j)
                        oK[(row0 + j) * 1024 + col] = (_Float16)(acc[1][mf][nf][j] + bb);
                } else {
                    const float bb = bv[col];
                    hfx4 pk;
#pragma unroll
                    for (int j = 0; j < 4; ++j) pk[j] = (_Float16)(acc[2][mf][nf][j] + bb);
                    *(hfx4*)&oV[((row0 >> 11) * 1024 + col) * 2048 + (row0 & 2047)] = pk;
                }
            }
        }
    }
}

// ---------------------------------------------------------------------------
// gemmMS: gemmQKV geometry on a single B matrix — 1 shared A-tile + 3
// ADJACENT 128-col B-strips as the 3 sets (192 block-MFMA per barrier
// pair). BM=128, BK=32, 64 KB LDS, 2 blocks/CU, counted vmcnt(8).
// Ragged tail: ns = min(3, NSTRIPS - 3*bx) (block-uniform); stage
// addresses for s >= ns clamp to the last strip (same load count ->
// identical vmcnt accounting), MFMA/epilogue skip s >= ns.
// A [M x K] lda + z*sAz; B [NSTRIPS*128 x K] ldb + z*sBz.
// OMODE 0: fp32 out = alpha*acc -> outF + z*sCz (ldc)   [PV]
// OMODE 2: fp16 out = (fp16)(alpha*acc) -> oH + z*sCz   [scores]
// ---------------------------------------------------------------------------
template <int OMODE>
__global__ __launch_bounds__(256, 2) void gemmMS(
    const _Float16* __restrict__ A, const _Float16* __restrict__ B0,
    float* __restrict__ outF, _Float16* __restrict__ oH,
    int K, int lda, int ldb, int ldc, float alpha,
    long sAz, long sBz, long sCz, int NSTRIPS)
{
    constexpr int BK = 32;
    __shared__ __attribute__((aligned(16))) _Float16 lds[2][4 * 128 * BK]; // 64 KB

    int bx, by, z;
    xcd_remap(bx, by, z);

    A += (long)z * sAz;
    const _Float16* B = B0 + (long)z * sBz;

    const int base = bx * 3;
    const int ns = min(3, NSTRIPS - base);

    const int tid = threadIdx.x;
    const int lane = tid & 63;
    const int wv = tid >> 6;
    const int wr = wv >> 1, wc = wv & 1;
    const int lr = lane & 15, lk = lane >> 4;

    const long m0 = (long)by * 128;

    fx4 acc[3][4][4] = {};

    auto STAGE = [&](int kt, int b) {
#pragma unroll
        for (int i = 0; i < 8; ++i) {
            const int slot = tid & 3;
            if (i < 2) {                 // A: 128 rows x 4 slots
                const int row = i * 64 + (tid >> 2);
                load_lds16(A + (m0 + row) * (long)lda + kt + ((slot ^ ((row >> 1) & 3)) << 3),
                           &lds[b][row * BK + slot * 8]);
            } else {                     // B: 3 strips x 128 rows x 4 slots
                const int which = (i - 2) >> 1;
                const int row = ((i - 2) & 1) * 64 + (tid >> 2);
                const int strip = min(base + which, NSTRIPS - 1);  // clamp tail
                load_lds16(B + ((long)strip * 128 + row) * (long)ldb + kt + ((slot ^ ((row >> 1) & 3)) << 3),
                           &lds[b][(1 + which) * 4096 + row * BK + slot * 8]);
            }
        }
    };

    const int NT = K / BK;
    STAGE(0, 0);
    STAGE(BK, 1);
    vmwait<8>();                         // tile 0 landed, tile 1 in flight
    __builtin_amdgcn_s_barrier();
    __builtin_amdgcn_sched_barrier(0);

    const int rA0 = wr * 64 + lr;
    const int rB0 = wc * 64 + lr;
    const int eA = (((rA0 >> 1) & 3) << 3);
    const int eB = (((rB0 >> 1) & 3) << 3);

    for (int t = 0; t < NT; ++t) {
        const _Float16* L = &lds[t & 1][0];

        hfx8 afr[4];
#pragma unroll
        for (int q = 0; q < 4; ++q)
            afr[q] = *(const hfx8*)&L[(rA0 + q * 16) * BK + ((lk * 8) ^ eA)];

#pragma unroll
        for (int s = 0; s < 3; ++s) {
            if (s < ns) {                // block-uniform branch
                hfx8 bfr[4];
#pragma unroll
                for (int nf = 0; nf < 4; ++nf)
                    bfr[nf] = *(const hfx8*)&L[(1 + s) * 4096 + (rB0 + nf * 16) * BK + ((lk * 8) ^ eB)];
                __builtin_amdgcn_s_setprio(1);
#pragma unroll
                for (int q = 0; q < 4; ++q)
#pragma unroll
                    for (int nf = 0; nf < 4; ++nf)
                        acc[s][q][nf] = __builtin_amdgcn_mfma_f32_16x16x32_f16(
                            afr[q], bfr[nf], acc[s][q][nf], 0, 0, 0);
                __builtin_amdgcn_s_setprio(0);
            }
        }

        __builtin_amdgcn_s_barrier();    // all waves done reading buf (t&1)
        if (t + 2 < NT) {
            STAGE((t + 2) * BK, t & 1);  // refill just-freed buffer
            vmwait<8>();                 // tile t+1 landed; t+2 in flight
        } else {
            vmwait<0>();                 // tail drain
        }
        __builtin_amdgcn_s_barrier();    // all waves see tile t+1 landed
        __builtin_amdgcn_sched_barrier(0);
    }

    // epilogue. D frag: col = lane&15, row = lk*4 + j
#pragma unroll
    for (int s = 0; s < 3; ++s) {
        if (s < ns) {
#pragma unroll
            for (int mf = 0; mf < 4; ++mf) {
#pragma unroll
                for (int nf = 0; nf < 4; ++nf) {
                    const long row0 = m0 + wr * 64 + mf * 16 + lk * 4;
                    const long col = (long)(base + s) * 128 + wc * 64 + nf * 16 + lr;
                    if constexpr (OMODE == 0) {
                        float* oz = outF + (long)z * sCz;
#pragma unroll
                        for (int j = 0; j < 4; ++j)
                            oz[(row0 + j) * (long)ldc + col] = alpha * acc[s][mf][nf][j];
                    } else {
                        _Float16* oz = oH + (long)z * sCz;
#pragma unroll
                        for (int j = 0; j < 4; ++j)
                            oz[(row0 + j) * (long)ldc + col] = (_Float16)(alpha * acc[s][mf][nf][j]);
                    }
                }
            }
        }
    }
}

// ---------------------------------------------------------------------------
// Row softmax over 2048 fp16 scores, fp32 math, fp16 probs IN PLACE.
// ---------------------------------------------------------------------------
__global__ __launch_bounds__(256) void softmax_kernel(_Float16* __restrict__ S)
{
    const long row = blockIdx.x;
    _Float16* r = S + row * 2048;
    const int t = threadIdx.x;

    const hfx8 hv = *(const hfx8*)&r[t * 8];
    float v[8];
#pragma unroll
    for (int j = 0; j < 8; ++j) v[j] = (float)hv[j];

    float mx = v[0];
#pragma unroll
    for (int j = 1; j < 8; ++j) mx = fmaxf(mx, v[j]);
#pragma unroll
    for (int o = 32; o; o >>= 1) mx = fmaxf(mx, __shfl_xor(mx, o, 64));

    __shared__ float redm[4];
    __shared__ float reds[4];
    const int w = t >> 6;
    if ((t & 63) == 0) redm[w] = mx;
    __syncthreads();
    mx = fmaxf(fmaxf(redm[0], redm[1]), fmaxf(redm[2], redm[3]));

    float e[8];
    float s = 0.f;
#pragma unroll
    for (int j = 0; j < 8; ++j) {
        e[j] = __expf(v[j] - mx);
        s += e[j];
    }
#pragma unroll
    for (int o = 32; o; o >>= 1) s += __shfl_xor(s, o, 64);
    if ((t & 63) == 0) reds[w] = s;
    __syncthreads();
    s = reds[0] + reds[1] + reds[2] + reds[3];

    const float inv = 1.0f / s;
    hfx8 p;
#pragma unroll
    for (int j = 0; j < 8; ++j) p[j] = (_Float16)(e[j] * inv);
    *(hfx8*)&r[t * 8] = p;
}

// ---------------------------------------------------------------------------
extern "C" void kernel_launch(void* const* d_in, const int* in_sizes, int n_in,
                              void* d_out, int out_size, void* d_ws, size_t ws_size,
                              hipStream_t stream)
{
    const float* x  = (const float*)d_in[0];
    const float* Wq = (const float*)d_in[1];
    const float* bq = (const float*)d_in[2];
    const float* Wk = (const float*)d_in[3];
    const float* bk = (const float*)d_in[4];
    const float* Wv = (const float*)d_in[5];
    const float* bv = (const float*)d_in[6];
    float* out = (float*)d_out;

    _Float16* xs  = (_Float16*)d_ws;            // [8192][1024] 16 MB
    _Float16* Wqh = xs + 8192ull * 1024;        // [1024][1024] 2 MB each
    _Float16* Wkh = Wqh + 1024ull * 1024;
    _Float16* Wvh = Wkh + 1024ull * 1024;
    _Float16* Qp  = Wvh + 1024ull * 1024;       // [8192][1024] 16 MB
    _Float16* Ks  = Qp + 8192ull * 1024;        // [8192][1024] 16 MB
    _Float16* Vt  = Ks + 8192ull * 1024;        // [4][1024][2048] 16 MB
    _Float16* Sh  = Vt + 4ull * 1024 * 2048;    // [4][2048][2048] fp16 32 MB

    dim3 blk(256);

    // 1) converts (merged single dispatch, plain fp16)
    conv_all_kernel<<<11264, blk, 0, stream>>>(
        (const float4*)x, xs,
        (const float4*)Wq, (const float4*)Wk, (const float4*)Wv, Wqh, Wkh, Wvh);

    // 2) fused QKV projection: 8 x 64 = 512 blocks = one tail-free round.
    gemmQKV<<<dim3(8, 64, 1), blk, 0, stream>>>(
        xs, Wqh, Wkh, Wvh, bq, bk, bv, Qp, Ks, Vt);

    // 3) scores: Q @ K^T (K=1024), fp16 out, 3-set strips (6x16x4 = 384 blocks)
    gemmMS<2><<<dim3(6, 16, 4), blk, 0, stream>>>(
        Qp, Ks, nullptr, Sh,
        1024, 1024, 1024, 2048, 1.0f,
        2097152L, 2097152L, 4194304L, 16);

    // 4) softmax (fp16 in/out, in place)
    softmax_kernel<<<2048 * 4, blk, 0, stream>>>(Sh);

    // 5) PV: P @ Vt^T (K=2048), fp32 out, 3-set strips (3x16x4 = 192 blocks)
    gemmMS<0><<<dim3(3, 16, 4), blk, 0, stream>>>(
        Sh, Vt, out, nullptr,
        2048, 2048, 2048, 1024, 0.03125f,
        4194304L, 2097152L, 2097152L, 8);
}

// Round 19
// 156.975 us; speedup vs baseline: 1.1825x; 1.1825x over previous
//
#include <hip/hip_runtime.h>

// ---------------------------------------------------------------------------
// Self-attention (B=4, N=2048, D=1024) on MI355X — fp16, round 19 (FINAL):
// Revert to R15/R17, the session best (156.7 us; 3.75x over round-1 589.9).
// Pipeline: fp32->fp16 convert (1 dispatch) -> fused QKV projection
// (gemmQKV: 1 shared A-tile + 3 B-sets, 192 block-MFMA per barrier pair,
// 64 KB LDS, 2 blocks/CU, counted vmcnt, both-sides swizzle, setprio, XCD
// remap) -> scores gemm2-BK64 fp16-out -> fp16 in-place softmax -> PV gemm2.
// Session-falsified alternatives: 8-phase ports (R7/R9), occupancy 4/CU
// (R10), 128x64 wave tiles (R11), algebraic K-elim (R12), gemmS 2-set
// (R16), gemmMS 3-strip (R18) — all regressed vs this configuration.
// ---------------------------------------------------------------------------

typedef _Float16 hfx8 __attribute__((ext_vector_type(8)));
typedef _Float16 hfx4 __attribute__((ext_vector_type(4)));
typedef float fx4 __attribute__((ext_vector_type(4)));

__device__ __forceinline__ void load_lds16(const void* g, void* l) {
    __builtin_amdgcn_global_load_lds(
        (const __attribute__((address_space(1))) void*)g,
        (__attribute__((address_space(3))) void*)l, 16, 0, 0);
}

template <int N> __device__ __forceinline__ void vmwait() {
    if constexpr (N == 8) asm volatile("s_waitcnt vmcnt(8)" ::: "memory");
    else asm volatile("s_waitcnt vmcnt(0)" ::: "memory");
}

// bijective XCD-chunked grid remap (T1, m204). Requires nwg % 8 == 0.
__device__ __forceinline__ void xcd_remap(int& x, int& y, int& z) {
    const int gx = gridDim.x, gy = gridDim.y;
    const int lin = blockIdx.x + gx * (blockIdx.y + gy * blockIdx.z);
    const int cpx = (gx * gy * gridDim.z) >> 3;
    const int w = (lin & 7) * cpx + (lin >> 3);
    x = w % gx;
    y = (w / gx) % gy;
    z = w / (gx * gy);
}

// ---------------------------------------------------------------------------
// merged converts: blocks [0,8192) -> x (8M floats), [8192,11264) -> Wq/Wk/Wv
// ---------------------------------------------------------------------------
__global__ __launch_bounds__(256) void conv_all_kernel(
    const float4* __restrict__ x, _Float16* __restrict__ xs,
    const float4* __restrict__ w0, const float4* __restrict__ w1, const float4* __restrict__ w2,
    _Float16* __restrict__ o0, _Float16* __restrict__ o1, _Float16* __restrict__ o2)
{
    const int b = blockIdx.x;
    const float4* in;
    _Float16* out;
    long i;
    if (b < 8192) {
        in = x; out = xs;
        i = (long)b * 256 + threadIdx.x;
    } else {
        const int wi = b - 8192;
        const int wsel = wi >> 10;
        in = wsel == 0 ? w0 : (wsel == 1 ? w1 : w2);
        out = wsel == 0 ? o0 : (wsel == 1 ? o1 : o2);
        i = (long)(wi & 1023) * 256 + threadIdx.x;
    }
    float4 v = in[i];
    hfx4 h;
    h[0] = (_Float16)v.x; h[1] = (_Float16)v.y;
    h[2] = (_Float16)v.z; h[3] = (_Float16)v.w;
    *(hfx4*)&out[i * 4] = h;
}

// ---------------------------------------------------------------------------
// gemmQKV (proven 35% MfmaUtil): fused Q/K/V projection.
// BM=BN=128, BK=32, 256 thr = 4 waves (2x2). LDS [A|Bq|Bk|Bv] x2 = 64 KB
// -> 2 blocks/CU. A-tile staged once per K-step, 3 B-sets (192 block-MFMA
// per barrier pair), acc[3][4][4]. Counted vmcnt(8), both-sides swizzle
// slot^=(row>>1)&3 (2-way, free), T5 setprio, T1 XCD remap.
// ---------------------------------------------------------------------------
__global__ __launch_bounds__(256, 2) void gemmQKV(
    const _Float16* __restrict__ A,
    const _Float16* __restrict__ Bq, const _Float16* __restrict__ Bk, const _Float16* __restrict__ Bv,
    const float* __restrict__ bq, const float* __restrict__ bk, const float* __restrict__ bv,
    _Float16* __restrict__ oQ, _Float16* __restrict__ oK, _Float16* __restrict__ oV)
{
    constexpr int BK = 32;
    __shared__ __attribute__((aligned(16))) _Float16 lds[2][4 * 128 * BK]; // 64 KB

    int bx, by, zz;
    xcd_remap(bx, by, zz);               // gridDim.z == 1 -> zz == 0

    const int tid = threadIdx.x;
    const int lane = tid & 63;
    const int wv = tid >> 6;
    const int wr = wv >> 1, wc = wv & 1; // 2x2 wave grid, 64x64 out each
    const int lr = lane & 15, lk = lane >> 4;

    const long m0 = (long)by * 128;
    const long n0 = (long)bx * 128;

    fx4 acc[3][4][4] = {};               // [output][q][nf], statically indexed

    auto STAGE = [&](int kt, int b) {
#pragma unroll
        for (int i = 0; i < 8; ++i) {
            const int slot = tid & 3;
            if (i < 2) {                 // A: 128 rows x 4 slots
                const int row = i * 64 + (tid >> 2);
                load_lds16(A + (m0 + row) * 1024L + kt + ((slot ^ ((row >> 1) & 3)) << 3),
                           &lds[b][row * BK + slot * 8]);
            } else {                     // B: 3 matrices x 128 rows x 4 slots
                const int which = (i - 2) >> 1;          // 0,0,1,1,2,2
                const int row = ((i - 2) & 1) * 64 + (tid >> 2);
                const _Float16* Bsel = which == 0 ? Bq : (which == 1 ? Bk : Bv);
                load_lds16(Bsel + (n0 + row) * 1024L + kt + ((slot ^ ((row >> 1) & 3)) << 3),
                           &lds[b][(1 + which) * 4096 + row * BK + slot * 8]);
            }
        }
    };

    const int NT = 32;
    STAGE(0, 0);
    STAGE(BK, 1);
    vmwait<8>();                         // tile 0 landed, tile 1 in flight
    __builtin_amdgcn_s_barrier();
    __builtin_amdgcn_sched_barrier(0);

    const int rA0 = wr * 64 + lr;
    const int rB0 = wc * 64 + lr;
    const int eA = (((rA0 >> 1) & 3) << 3);  // invariant under +16q
    const int eB = (((rB0 >> 1) & 3) << 3);

    for (int t = 0; t < NT; ++t) {
        const _Float16* L = &lds[t & 1][0];

        hfx8 afr[4];
#pragma unroll
        for (int q = 0; q < 4; ++q)
            afr[q] = *(const hfx8*)&L[(rA0 + q * 16) * BK + ((lk * 8) ^ eA)];

#pragma unroll
        for (int w3 = 0; w3 < 3; ++w3) {
            hfx8 bfr[4];
#pragma unroll
            for (int nf = 0; nf < 4; ++nf)
                bfr[nf] = *(const hfx8*)&L[(1 + w3) * 4096 + (rB0 + nf * 16) * BK + ((lk * 8) ^ eB)];
            __builtin_amdgcn_s_setprio(1);
#pragma unroll
            for (int q = 0; q < 4; ++q)
#pragma unroll
                for (int nf = 0; nf < 4; ++nf)
                    acc[w3][q][nf] = __builtin_amdgcn_mfma_f32_16x16x32_f16(
                        afr[q], bfr[nf], acc[w3][q][nf], 0, 0, 0);
            __builtin_amdgcn_s_setprio(0);
        }

        __builtin_amdgcn_s_barrier();    // all waves done reading buf (t&1)
        if (t + 2 < NT) {
            STAGE((t + 2) * BK, t & 1);  // refill just-freed buffer
            vmwait<8>();                 // tile t+1 landed; t+2 in flight
        } else {
            vmwait<0>();                 // tail drain
        }
        __builtin_amdgcn_s_barrier();    // all waves see tile t+1 landed
        __builtin_amdgcn_sched_barrier(0);
    }

    // epilogue. D frag: col = lane&15, row = lk*4 + j
#pragma unroll
    for (int w3 = 0; w3 < 3; ++w3) {
#pragma unroll
        for (int mf = 0; mf < 4; ++mf) {
#pragma unroll
            for (int nf = 0; nf < 4; ++nf) {
                const long row0 = m0 + wr * 64 + mf * 16 + lk * 4;
                const long col = n0 + wc * 64 + nf * 16 + lr;
                if (w3 == 0) {
                    const float bb = bq[col];
#pragma unroll
                    for (int j = 0; j < 4; ++j)
                        oQ[(row0 + j) * 1024 + col] = (_Float16)(acc[0][mf][nf][j] + bb);
                } else if (w3 == 1) {
                    const float bb = bk[col];
#pragma unroll
                    for (int j = 0; j < 4; ++j)
                        oK[(row0 + j) * 1024 + col] = (_Float16)(acc[1][mf][nf][j] + bb);
                } else {
                    const float bb = bv[col];
                    hfx4 pk;
#pragma unroll
                    for (int j = 0; j < 4; ++j) pk[j] = (_Float16)(acc[2][mf][nf][j] + bb);
                    *(hfx4*)&oV[((row0 >> 11) * 1024 + col) * 2048 + (row0 & 2047)] = pk;
                }
            }
        }
    }
}

// ---------------------------------------------------------------------------
// Proven 2-phase pipelined GEMM. BM=BN=128, BK=64, 256 thr = 4 waves (2x2),
// 64 KB LDS -> 2 blocks/CU, NT=16. Counted-vmcnt double-buffer, raw
// s_barrier only, T2 both-sides swizzle, T5 setprio, T1 XCD remap.
// A [M x K] row-major lda; B [N x K] row-major ldb; B = Bq + z*sBz.
// OMODE 0: fp32 out = alpha*acc -> outF + z*sCz (ldc)
// OMODE 2: fp16 out = (fp16)(alpha*acc) -> oH + z*sCz (ldc)
// ---------------------------------------------------------------------------
template <int OMODE>
__global__ __launch_bounds__(256, 2) void gemm2(
    const _Float16* __restrict__ A, const _Float16* __restrict__ Bq,
    float* __restrict__ outF, _Float16* __restrict__ oH,
    int K, int lda, int ldb, int ldc, float alpha,
    long sAz, long sBz, long sCz)
{
    constexpr int BM = 128, BN = 128, BK = 64;
    constexpr int LPT = 8;

    __shared__ __attribute__((aligned(16))) _Float16 lds[2][(BM + BN) * BK];

    int bx, by, z;
    xcd_remap(bx, by, z);

    A += (long)z * sAz;
    const _Float16* B = Bq + (long)z * sBz;

    const int tid = threadIdx.x;
    const int lane = tid & 63;
    const int wv = tid >> 6;
    const int wr = wv >> 1, wc = wv & 1;
    const int lr = lane & 15, lk = lane >> 4;

    const long m0 = (long)by * BM;
    const long n0 = (long)bx * BN;

    fx4 acc[4][4] = {};

    auto STAGE = [&](int kt, int b) {
#pragma unroll
        for (int i = 0; i < LPT; ++i) {
            const int c = i * 256 + tid;
            if (i < 4) {
                const int row = c >> 3, slot = c & 7;
                load_lds16(A + (m0 + row) * (long)lda + kt + ((slot ^ (row & 7)) << 3),
                           &lds[b][c * 8]);
            } else {
                const int c2 = c - 1024;
                const int row = c2 >> 3, slot = c2 & 7;
                load_lds16(B + (n0 + row) * (long)ldb + kt + ((slot ^ (row & 7)) << 3),
                           &lds[b][BM * BK + c2 * 8]);
            }
        }
    };

    const int NT = K / BK;
    STAGE(0, 0);
    STAGE(BK, 1);
    vmwait<8>();
    __builtin_amdgcn_s_barrier();
    __builtin_amdgcn_sched_barrier(0);

    const int rA0 = wr * 64 + lr;
    const int rB0 = wc * 64 + lr;
    const int eA = (rA0 & 7) << 3;
    const int eB = (rB0 & 7) << 3;

    for (int t = 0; t < NT; ++t) {
        const _Float16* LA = &lds[t & 1][0];
        const _Float16* LB = LA + BM * BK;

        hfx8 bfr[4][2];
#pragma unroll
        for (int nf = 0; nf < 4; ++nf)
#pragma unroll
            for (int ks = 0; ks < 2; ++ks)
                bfr[nf][ks] = *(const hfx8*)&LB[(rB0 + nf * 16) * BK + ((ks * 32 + lk * 8) ^ eB)];

#pragma unroll
        for (int q = 0; q < 4; ++q) {
            hfx8 afr[2];
#pragma unroll
            for (int ks = 0; ks < 2; ++ks)
                afr[ks] = *(const hfx8*)&LA[(rA0 + q * 16) * BK + ((ks * 32 + lk * 8) ^ eA)];
            __builtin_amdgcn_s_setprio(1);
#pragma unroll
            for (int nf = 0; nf < 4; ++nf)
#pragma unroll
                for (int ks = 0; ks < 2; ++ks)
                    acc[q][nf] = __builtin_amdgcn_mfma_f32_16x16x32_f16(
                        afr[ks], bfr[nf][ks], acc[q][nf], 0, 0, 0);
            __builtin_amdgcn_s_setprio(0);
        }

        __builtin_amdgcn_s_barrier();
        if (t + 2 < NT) {
            STAGE((t + 2) * BK, t & 1);
            vmwait<8>();
        } else {
            vmwait<0>();
        }
        __builtin_amdgcn_s_barrier();
        __builtin_amdgcn_sched_barrier(0);
    }

#pragma unroll
    for (int mf = 0; mf < 4; ++mf) {
#pragma unroll
        for (int nf = 0; nf < 4; ++nf) {
            const long row0 = m0 + wr * 64 + mf * 16 + lk * 4;
            const long col = n0 + wc * 64 + nf * 16 + lr;
            if constexpr (OMODE == 0) {
                float* oz = outF + (long)z * sCz;
#pragma unroll
                for (int j = 0; j < 4; ++j)
                    oz[(row0 + j) * (long)ldc + col] = alpha * acc[mf][nf][j];
            } else {
                _Float16* oz = oH + (long)z * sCz;
#pragma unroll
                for (int j = 0; j < 4; ++j)
                    oz[(row0 + j) * (long)ldc + col] = (_Float16)(alpha * acc[mf][nf][j]);
            }
        }
    }
}

// ---------------------------------------------------------------------------
// Row softmax over 2048 fp16 scores, fp32 math, fp16 probs IN PLACE.
// ---------------------------------------------------------------------------
__global__ __launch_bounds__(256) void softmax_kernel(_Float16* __restrict__ S)
{
    const long row = blockIdx.x;
    _Float16* r = S + row * 2048;
    const int t = threadIdx.x;

    const hfx8 hv = *(const hfx8*)&r[t * 8];
    float v[8];
#pragma unroll
    for (int j = 0; j < 8; ++j) v[j] = (float)hv[j];

    float mx = v[0];
#pragma unroll
    for (int j = 1; j < 8; ++j) mx = fmaxf(mx, v[j]);
#pragma unroll
    for (int o = 32; o; o >>= 1) mx = fmaxf(mx, __shfl_xor(mx, o, 64));

    __shared__ float redm[4];
    __shared__ float reds[4];
    const int w = t >> 6;
    if ((t & 63) == 0) redm[w] = mx;
    __syncthreads();
    mx = fmaxf(fmaxf(redm[0], redm[1]), fmaxf(redm[2], redm[3]));

    float e[8];
    float s = 0.f;
#pragma unroll
    for (int j = 0; j < 8; ++j) {
        e[j] = __expf(v[j] - mx);
        s += e[j];
    }
#pragma unroll
    for (int o = 32; o; o >>= 1) s += __shfl_xor(s, o, 64);
    if ((t & 63) == 0) reds[w] = s;
    __syncthreads();
    s = reds[0] + reds[1] + reds[2] + reds[3];

    const float inv = 1.0f / s;
    hfx8 p;
#pragma unroll
    for (int j = 0; j < 8; ++j) p[j] = (_Float16)(e[j] * inv);
    *(hfx8*)&r[t * 8] = p;
}

// ---------------------------------------------------------------------------
extern "C" void kernel_launch(void* const* d_in, const int* in_sizes, int n_in,
                              void* d_out, int out_size, void* d_ws, size_t ws_size,
                              hipStream_t stream)
{
    const float* x  = (const float*)d_in[0];
    const float* Wq = (const float*)d_in[1];
    const float* bq = (const float*)d_in[2];
    const float* Wk = (const float*)d_in[3];
    const float* bk = (const float*)d_in[4];
    const float* Wv = (const float*)d_in[5];
    const float* bv = (const float*)d_in[6];
    float* out = (float*)d_out;

    _Float16* xs  = (_Float16*)d_ws;            // [8192][1024] 16 MB
    _Float16* Wqh = xs + 8192ull * 1024;        // [1024][1024] 2 MB each
    _Float16* Wkh = Wqh + 1024ull * 1024;
    _Float16* Wvh = Wkh + 1024ull * 1024;
    _Float16* Qp  = Wvh + 1024ull * 1024;       // [8192][1024] 16 MB
    _Float16* Ks  = Qp + 8192ull * 1024;        // [8192][1024] 16 MB
    _Float16* Vt  = Ks + 8192ull * 1024;        // [4][1024][2048] 16 MB
    _Float16* Sh  = Vt + 4ull * 1024 * 2048;    // [4][2048][2048] fp16 32 MB

    dim3 blk(256);

    // 1) converts (merged single dispatch, plain fp16)
    conv_all_kernel<<<11264, blk, 0, stream>>>(
        (const float4*)x, xs,
        (const float4*)Wq, (const float4*)Wk, (const float4*)Wv, Wqh, Wkh, Wvh);

    // 2) fused QKV projection: 8 x 64 = 512 blocks = one tail-free round.
    gemmQKV<<<dim3(8, 64, 1), blk, 0, stream>>>(
        xs, Wqh, Wkh, Wvh, bq, bk, bv, Qp, Ks, Vt);

    // 3) scores: Q @ K^T (K=1024), fp16 out, z=4  (16x16x4 = 1024 blocks)
    gemm2<2><<<dim3(16, 16, 4), blk, 0, stream>>>(
        Qp, Ks, nullptr, Sh,
        1024, 1024, 1024, 2048, 1.0f,
        2097152L, 2097152L, 4194304L);

    // 4) softmax (fp16 in/out, in place)
    softmax_kernel<<<2048 * 4, blk, 0, stream>>>(Sh);

    // 5) PV: P @ Vt^T, alpha = 1/32, fp32 out, z=4  (8x16x4 = 512 blocks)
    gemm2<0><<<dim3(8, 16, 4), blk, 0, stream>>>(
        Sh, Vt, out, nullptr,
        2048, 2048, 2048, 1024, 0.03125f,
        4194304L, 2097152L, 2097152L);
}